// Round 24
// baseline (193.410 us; speedup 1.0000x reference)
//
#include <hip/hip_runtime.h>
#include <hip/hip_fp16.h>

#define B_ 64
#define N_ 4096
#define C_ 10
#define D_ 8
#define E_ 16
#define EPS_ 1e-7f
#define NT_ 8
#define NBLK_ (N_ / NT_)          // 512 pass blocks
#define NSLOT_ NBLK_              // 512 partial slots (1 per block)
#define PROW_ 80                  // u32 per partial row (160 halfs)
#define WBROW_ 82                 // padded LDS combine row stride (u32)
#define NSG_ 8                    // reduce stage-A slot groups

typedef _Float16 h2_t __attribute__((ext_vector_type(2)));
typedef __fp16   p2_t __attribute__((ext_vector_type(2)));   // cvt_pkrtz ret type

__device__ inline unsigned pkh(float a, float b) {   // f32x2 -> packed fp16
    p2_t t = __builtin_amdgcn_cvt_pkrtz(a, b);
    return *(unsigned*)&t;
}
#if __has_builtin(__builtin_amdgcn_fdot2)
__device__ inline float fd2(unsigned a, unsigned b, float c) {
    h2_t av = *(h2_t*)&a, bv = *(h2_t*)&b;
    return __builtin_amdgcn_fdot2(av, bv, c, false);
}
#else
__device__ inline float fd2(unsigned a, unsigned b, float c) {
    h2_t av = *(h2_t*)&a, bv = *(h2_t*)&b;
    return fmaf((float)av.x, (float)bv.x, fmaf((float)av.y, (float)bv.y, c));
}
#endif
__device__ inline float hlo(unsigned u) { h2_t t = *(h2_t*)&u; return (float)t.x; }
__device__ inline float hhi(unsigned u) { h2_t t = *(h2_t*)&u; return (float)t.y; }
__device__ inline unsigned hpack(float a, float b) {
    __half2 t = __floats2half2_rn(a, b);
    return *(unsigned*)&t;
}
__device__ inline float2 hunpack(unsigned u) {
    return __half22float2(*(const __half2*)&u);
}

// Block: 512 thr = 8 waves = (h: b-half) x (cg: c-half) x (np: n-half).
// Thread owns TWO b (b0=h*32+bl, b1=b0+16), FIVE c, 4 n. fp16 d-pair data,
// v_dot2_f32_f16; np halves combine via fp16 LDS -> ONE slot per block.
// (R22 structure — best measured: 78.0 us.) pass<true> also zeroes cnt.
template <bool UNIFORM>
__global__ __launch_bounds__(512, 4) void caps_pass(
    const float* __restrict__ x, const float* __restrict__ W,
    const unsigned* __restrict__ vpk, unsigned* __restrict__ partial,
    int* __restrict__ cnt)
{
    __shared__ __align__(16) char smem[30720];
    uint4*    wlds = (uint4*)smem;                   // 1280 uint4 = 20480 B
    unsigned* xlds = (unsigned*)(smem + 20480);      // 2048 u32  =  8192 B
    float*    xch  = (float*)(smem + 28672);         // 512 f32   =  2048 B
    unsigned* wb   = (unsigned*)smem;                // combine alias (20992 B)

    const int tid = (int)threadIdx.x;
    const int blk = (int)blockIdx.x;
    const int n0  = blk * NT_;

    if (UNIFORM && blk == 0 && tid < B_) cnt[tid] = 0;   // covers 0xAA poison

    // ---- stage W -> LDS fp16 d-pair granules [n][c][d2][eq] ----
    {
        const float4* wg = (const float4*)W + (size_t)blk * (NT_ * 320);
#pragma unroll
        for (int k = 0; k < 3; ++k) {
            const int g = k * 512 + tid;          // [0, 1280)
            if (g < NT_ * C_ * 16) {
                const int n   = g / 160;
                const int rem = g - n * 160;
                const int c   = rem >> 4;
                const int r2  = rem & 15;
                const int d2  = r2 >> 2;
                const int eqs = r2 & 3;
                const float4 g0 = wg[n * 320 + c * 32 + (2 * d2) * 4 + eqs];
                const float4 g1 = wg[n * 320 + c * 32 + (2 * d2 + 1) * 4 + eqs];
                wlds[((n * C_ + c) * 4 + d2) * 4 + eqs] =
                    make_uint4(pkh(g0.x, g1.x), pkh(g0.y, g1.y),
                               pkh(g0.z, g1.z), pkh(g0.w, g1.w));
            }
        }
    }
    // ---- stage x -> LDS fp16 d-pair words [n][b][4] ----
    {
        const float4* xg = (const float4*)x;
#pragma unroll
        for (int k = 0; k < 2; ++k) {
            const int g = k * 512 + tid;          // [0, 1024)
            const int b = g >> 4;
            const int r = g & 15;
            const int n = r >> 1;
            const int dq = r & 1;
            const float4 v = xg[((size_t)b * N_ + n0 + n) * 2 + dq];
            *(uint2*)&xlds[(n * B_ + b) * 4 + dq * 2] =
                make_uint2(pkh(v.x, v.y), pkh(v.z, v.w));
        }
    }
    __syncthreads();

    const int wv   = tid >> 6;
    const int lane = tid & 63;
    const int eq   = lane & 3;
    const int bl   = lane >> 2;
    const int h    = wv & 1;
    const int cg   = (wv >> 1) & 1;    // c-half: 0 -> c 0..4, 1 -> c 5..9
    const int np   = wv >> 2;          // n-half: 4 n each
    const int b0   = h * 32 + bl;
    const int b1   = b0 + 16;
    const int cbase = cg * 5;
    // xch slot: [cg][np*2+h][bl][2]
    float* xme = xch + (((cg) * 4 + np * 2 + h) * 16 + bl) * 2;
    float* xot = xch + (((cg ^ 1) * 4 + np * 2 + h) * 16 + bl) * 2;

    unsigned vcp0[5][2], vcp1[5][2];
    if (!UNIFORM) {
#pragma unroll
        for (int cc = 0; cc < 5; ++cc) {
            const int c = cbase + cc;
            const uint2 a = *(const uint2*)(vpk + (b0 * C_ + c) * 8 + eq * 2);
            vcp0[cc][0] = a.x; vcp0[cc][1] = a.y;
            const uint2 d = *(const uint2*)(vpk + (b1 * C_ + c) * 8 + eq * 2);
            vcp1[cc][0] = d.x; vcp1[cc][1] = d.y;
        }
    }

    float4 acc0[5], acc1[5];
#pragma unroll
    for (int cc = 0; cc < 5; ++cc) {
        acc0[cc] = make_float4(0.f, 0.f, 0.f, 0.f);
        acc1[cc] = make_float4(0.f, 0.f, 0.f, 0.f);
    }

#pragma unroll 1
    for (int j = 0; j < 4; ++j) {
        const int nl = np * 4 + j;
        const uint4 xq0 = *(const uint4*)&xlds[(nl * B_ + b0) * 4];
        const uint4 xq1 = *(const uint4*)&xlds[(nl * B_ + b1) * 4];
        const unsigned xa[4] = {xq0.x, xq0.y, xq0.z, xq0.w};
        const unsigned xb[4] = {xq1.x, xq1.y, xq1.z, xq1.w};

        if (UNIFORM) {
#pragma unroll
            for (int cc = 0; cc < 5; ++cc) {
                const uint4* wq = &wlds[(nl * C_ + cbase + cc) * 16];
#pragma unroll
                for (int d2 = 0; d2 < 4; ++d2) {
                    const uint4 q = wq[d2 * 4 + eq];
                    acc0[cc].x = fd2(xa[d2], q.x, acc0[cc].x);
                    acc0[cc].y = fd2(xa[d2], q.y, acc0[cc].y);
                    acc0[cc].z = fd2(xa[d2], q.z, acc0[cc].z);
                    acc0[cc].w = fd2(xa[d2], q.w, acc0[cc].w);
                    acc1[cc].x = fd2(xb[d2], q.x, acc1[cc].x);
                    acc1[cc].y = fd2(xb[d2], q.y, acc1[cc].y);
                    acc1[cc].z = fd2(xb[d2], q.z, acc1[cc].z);
                    acc1[cc].w = fd2(xb[d2], q.w, acc1[cc].w);
                }
            }
        } else {
            unsigned uhp0[5][2], uhp1[5][2];
            float wgt0[5], wgt1[5];
            float s0 = 0.f, s1 = 0.f;
#pragma unroll
            for (int cc = 0; cc < 5; ++cc) {
                const uint4* wq = &wlds[(nl * C_ + cbase + cc) * 16];
                float4 u0 = make_float4(0.f, 0.f, 0.f, 0.f);
                float4 u1 = make_float4(0.f, 0.f, 0.f, 0.f);
#pragma unroll
                for (int d2 = 0; d2 < 4; ++d2) {
                    const uint4 q = wq[d2 * 4 + eq];
                    u0.x = fd2(xa[d2], q.x, u0.x);
                    u0.y = fd2(xa[d2], q.y, u0.y);
                    u0.z = fd2(xa[d2], q.z, u0.z);
                    u0.w = fd2(xa[d2], q.w, u0.w);
                    u1.x = fd2(xb[d2], q.x, u1.x);
                    u1.y = fd2(xb[d2], q.y, u1.y);
                    u1.z = fd2(xb[d2], q.z, u1.z);
                    u1.w = fd2(xb[d2], q.w, u1.w);
                }
                const unsigned up00 = pkh(u0.x, u0.y), up01 = pkh(u0.z, u0.w);
                const unsigned up10 = pkh(u1.x, u1.y), up11 = pkh(u1.z, u1.w);
                float t0 = fd2(up00, vcp0[cc][0], fd2(up01, vcp0[cc][1], 0.f));
                t0 += __shfl_xor(t0, 1); t0 += __shfl_xor(t0, 2);
                float t1 = fd2(up10, vcp1[cc][0], fd2(up11, vcp1[cc][1], 0.f));
                t1 += __shfl_xor(t1, 1); t1 += __shfl_xor(t1, 2);
                wgt0[cc] = __expf(t0); s0 += wgt0[cc];
                wgt1[cc] = __expf(t1); s1 += wgt1[cc];
                uhp0[cc][0] = up00; uhp0[cc][1] = up01;
                uhp1[cc][0] = up10; uhp1[cc][1] = up11;
            }
            // exchange the 5-class exp-sums with the other c-half
            if (eq == 0) { xme[0] = s0; xme[1] = s1; }
            __syncthreads();
            const float i0 = 1.f / (s0 + xot[0]);
            const float i1 = 1.f / (s1 + xot[1]);
#pragma unroll
            for (int cc = 0; cc < 5; ++cc) {
                const float g0 = wgt0[cc] * i0, g1 = wgt1[cc] * i1;
                acc0[cc].x = fmaf(g0, hlo(uhp0[cc][0]), acc0[cc].x);
                acc0[cc].y = fmaf(g0, hhi(uhp0[cc][0]), acc0[cc].y);
                acc0[cc].z = fmaf(g0, hlo(uhp0[cc][1]), acc0[cc].z);
                acc0[cc].w = fmaf(g0, hhi(uhp0[cc][1]), acc0[cc].w);
                acc1[cc].x = fmaf(g1, hlo(uhp1[cc][0]), acc1[cc].x);
                acc1[cc].y = fmaf(g1, hhi(uhp1[cc][0]), acc1[cc].y);
                acc1[cc].z = fmaf(g1, hlo(uhp1[cc][1]), acc1[cc].z);
                acc1[cc].w = fmaf(g1, hhi(uhp1[cc][1]), acc1[cc].w);
            }
        }
    }

    // ---- combine np halves via fp16 LDS (alias over dead W/x) ----
    const float fold = UNIFORM ? 0.1f : 1.f;   // softmax(0) = 1/10 folded out
    __syncthreads();   // all wlds/xlds reads done; smem becomes wb
    if (np == 1) {
#pragma unroll
        for (int cc = 0; cc < 5; ++cc) {
            const int c = cbase + cc;
            *(uint2*)&wb[b0 * WBROW_ + c * 8 + eq * 2] =
                make_uint2(hpack(acc0[cc].x * fold, acc0[cc].y * fold),
                           hpack(acc0[cc].z * fold, acc0[cc].w * fold));
            *(uint2*)&wb[b1 * WBROW_ + c * 8 + eq * 2] =
                make_uint2(hpack(acc1[cc].x * fold, acc1[cc].y * fold),
                           hpack(acc1[cc].z * fold, acc1[cc].w * fold));
        }
    }
    __syncthreads();
    if (np == 0) {
#pragma unroll
        for (int cc = 0; cc < 5; ++cc) {
            const int c = cbase + cc;
            const uint2 p0 = *(const uint2*)&wb[b0 * WBROW_ + c * 8 + eq * 2];
            const float2 a0 = hunpack(p0.x), a1 = hunpack(p0.y);
            *(uint2*)(partial + ((size_t)b0 * NSLOT_ + blk) * PROW_ + c * 8 + eq * 2) =
                make_uint2(hpack(a0.x + acc0[cc].x * fold, a0.y + acc0[cc].y * fold),
                           hpack(a1.x + acc0[cc].z * fold, a1.y + acc0[cc].w * fold));
            const uint2 p1 = *(const uint2*)&wb[b1 * WBROW_ + c * 8 + eq * 2];
            const float2 d0 = hunpack(p1.x), d1 = hunpack(p1.y);
            *(uint2*)(partial + ((size_t)b1 * NSLOT_ + blk) * PROW_ + c * 8 + eq * 2) =
                make_uint2(hpack(d0.x + acc1[cc].x * fold, d0.y + acc1[cc].y * fold),
                           hpack(d1.x + acc1[cc].z * fold, d1.y + acc1[cc].w * fold));
        }
    }
}

// Merged reduce: 512 blocks = (b, sg). Phase A (= proven redA): sum 64 slots
// -> sub[b][sg][160] f32. Then last-arriver per b (fence + device atomicAdd,
// G12/G16 release-acquire) re-reads sub[b][*] (L2-hot) and does the redB
// squash in-block; resets cnt[b]=0 (self-cleaning for graph replay).
// mode: 0 = v_cum = v, 1 = v_cum += v, 2 = out = v
__global__ __launch_bounds__(256) void caps_redAB(
    const unsigned* __restrict__ partial, float* __restrict__ sub,
    float* __restrict__ v_cum, unsigned* __restrict__ vpk,
    float* __restrict__ out, int* __restrict__ cnt, int mode)
{
    const int b  = (int)blockIdx.x >> 3;
    const int sg = (int)blockIdx.x & 7;
    const int tid = (int)threadIdx.x;
    const int sc   = tid >> 5;          // 0..7
    const int col4 = tid & 31;          // active < 20
    __shared__ float red[8][20][8];
    __shared__ int lastf;
    if (col4 < 20) {
        float s[8];
#pragma unroll
        for (int p = 0; p < 8; ++p) s[p] = 0.f;
        const int slot0 = sg * (NSLOT_ / NSG_) + sc * 8;
        const uint4* base = (const uint4*)(partial +
            ((size_t)b * NSLOT_ + slot0) * PROW_) + col4;
#pragma unroll 4
        for (int k = 0; k < 8; ++k) {
            const uint4 q = base[k * (PROW_ / 4)];
            const float2 f0 = hunpack(q.x), f1 = hunpack(q.y);
            const float2 f2 = hunpack(q.z), f3 = hunpack(q.w);
            s[0] += f0.x; s[1] += f0.y; s[2] += f1.x; s[3] += f1.y;
            s[4] += f2.x; s[5] += f2.y; s[6] += f3.x; s[7] += f3.y;
        }
#pragma unroll
        for (int p = 0; p < 8; ++p) red[sc][col4][p] = s[p];
    }
    __syncthreads();
    if (tid < 160) {
        const int c4 = tid >> 3, p = tid & 7;
        float s = 0.f;
#pragma unroll
        for (int ch = 0; ch < 8; ++ch) s += red[ch][c4][p];
        sub[((size_t)b * NSG_ + sg) * (C_ * E_) + c4 * 8 + p] = s;
    }

    // ---- last-block-per-b reduction (release: fence + atomic) ----
    __threadfence();
    if (tid == 0) lastf = (atomicAdd(&cnt[b], 1) == NSG_ - 1) ? 1 : 0;
    __syncthreads();
    if (!lastf) return;
    __threadfence();                    // acquire side
    if (tid == 0) cnt[b] = 0;           // self-clean for next iter / replay

    if (tid < PROW_) {
        float slo = 0.f, shi = 0.f;
#pragma unroll
        for (int g = 0; g < NSG_; ++g) {
            const float* p = sub + ((size_t)b * NSG_ + g) * (C_ * E_) + tid * 2;
            slo += p[0]; shi += p[1];
        }
        float p = slo * slo + shi * shi;   // sum over the 16 e of this c
        p += __shfl_xor(p, 1); p += __shfl_xor(p, 2); p += __shfl_xor(p, 4);
        const float sc2 = (p / (1.f + p)) * rsqrtf(p + EPS_);
        float v0 = sc2 * slo, v1 = sc2 * shi;
        const int o = b * (C_ * E_) + tid * 2;
        if (mode == 2) {
            out[o] = v0; out[o + 1] = v1;
        } else {
            if (mode == 0) {
                v_cum[o] = v0; v_cum[o + 1] = v1;
            } else {
                v0 += v_cum[o]; v1 += v_cum[o + 1];
                v_cum[o] = v0; v_cum[o + 1] = v1;
            }
            vpk[b * PROW_ + tid] = hpack(v0, v1);
        }
    }
}

extern "C" void kernel_launch(void* const* d_in, const int* in_sizes, int n_in,
                              void* d_out, int out_size, void* d_ws, size_t ws_size,
                              hipStream_t stream) {
    const float* x = (const float*)d_in[0];
    const float* W = (const float*)d_in[1];
    float* out = (float*)d_out;

    // ws: partial 10.49 MB | sub 327 KB | v_cum 40 KB | vpk 20 KB | cnt 256 B
    char* p = (char*)d_ws;
    unsigned* partial = (unsigned*)p;
    p += (size_t)B_ * NSLOT_ * PROW_ * sizeof(unsigned);
    float* sub = (float*)p;
    p += (size_t)B_ * NSG_ * C_ * E_ * sizeof(float);
    float* v_cum = (float*)p;
    p += (size_t)B_ * C_ * E_ * sizeof(float);
    unsigned* vpk = (unsigned*)p;
    p += (size_t)B_ * PROW_ * sizeof(unsigned);
    int* cnt = (int*)p;

    for (int t = 0; t < 3; ++t) {
        if (t == 0)
            caps_pass<true ><<<dim3(NBLK_), 512, 0, stream>>>(x, W, vpk, partial, cnt);
        else
            caps_pass<false><<<dim3(NBLK_), 512, 0, stream>>>(x, W, vpk, partial, cnt);
        caps_redAB<<<dim3(B_ * NSG_), 256, 0, stream>>>(partial, sub, v_cum, vpk, out, cnt, t);
    }
}

// Round 25
// 78.228 us; speedup vs baseline: 2.4724x; 2.4724x over previous
//
#include <hip/hip_runtime.h>
#include <hip/hip_fp16.h>

#define B_ 64
#define N_ 4096
#define C_ 10
#define D_ 8
#define E_ 16
#define EPS_ 1e-7f
#define NT_ 8
#define NBLK_ (N_ / NT_)          // 512 pass blocks
#define NSLOT_ NBLK_              // 512 partial slots (1 per block)
#define PROW_ 80                  // u32 per partial row (160 halfs)
#define WBROW_ 82                 // padded LDS combine row stride (u32)
#define NSG_ 8                    // reduce stage-A slot groups

typedef _Float16 h2_t __attribute__((ext_vector_type(2)));
typedef __fp16   p2_t __attribute__((ext_vector_type(2)));   // cvt_pkrtz ret type

__device__ inline unsigned pkh(float a, float b) {   // f32x2 -> packed fp16
    p2_t t = __builtin_amdgcn_cvt_pkrtz(a, b);
    return *(unsigned*)&t;
}
#if __has_builtin(__builtin_amdgcn_fdot2)
__device__ inline float fd2(unsigned a, unsigned b, float c) {
    h2_t av = *(h2_t*)&a, bv = *(h2_t*)&b;
    return __builtin_amdgcn_fdot2(av, bv, c, false);
}
#else
__device__ inline float fd2(unsigned a, unsigned b, float c) {
    h2_t av = *(h2_t*)&a, bv = *(h2_t*)&b;
    return fmaf((float)av.x, (float)bv.x, fmaf((float)av.y, (float)bv.y, c));
}
#endif
__device__ inline float hlo(unsigned u) { h2_t t = *(h2_t*)&u; return (float)t.x; }
__device__ inline float hhi(unsigned u) { h2_t t = *(h2_t*)&u; return (float)t.y; }
__device__ inline unsigned hpack(float a, float b) {
    __half2 t = __floats2half2_rn(a, b);
    return *(unsigned*)&t;
}
__device__ inline float2 hunpack(unsigned u) {
    return __half22float2(*(const __half2*)&u);
}

// Block: 512 thr = 8 waves = (h: b-half) x (cg: c-half) x (np: n-half).
// Thread owns TWO b (b0=h*32+bl, b1=b0+16), FIVE c, 4 n (np half of NT=8).
// fp16 d-pair data, v_dot2_f32_f16 contraction; v_cum arrives pre-packed
// (vpk). np halves combine via fp16 LDS buffer (aliased over dead W tile)
// -> ONE slot per block: partial = 10.5 MB. (R22 — best measured: 78.0 us.)
template <bool UNIFORM>
__global__ __launch_bounds__(512, 4) void caps_pass(
    const float* __restrict__ x, const float* __restrict__ W,
    const unsigned* __restrict__ vpk, unsigned* __restrict__ partial)
{
    __shared__ __align__(16) char smem[30720];
    uint4*    wlds = (uint4*)smem;                   // 1280 uint4 = 20480 B
    unsigned* xlds = (unsigned*)(smem + 20480);      // 2048 u32  =  8192 B
    float*    xch  = (float*)(smem + 28672);         // 512 f32   =  2048 B
    unsigned* wb   = (unsigned*)smem;                // combine alias (20992 B)

    const int tid = (int)threadIdx.x;
    const int blk = (int)blockIdx.x;
    const int n0  = blk * NT_;

    // ---- stage W -> LDS fp16 d-pair granules [n][c][d2][eq] ----
    {
        const float4* wg = (const float4*)W + (size_t)blk * (NT_ * 320);
#pragma unroll
        for (int k = 0; k < 3; ++k) {
            const int g = k * 512 + tid;          // [0, 1280)
            if (g < NT_ * C_ * 16) {
                const int n   = g / 160;
                const int rem = g - n * 160;
                const int c   = rem >> 4;
                const int r2  = rem & 15;
                const int d2  = r2 >> 2;
                const int eqs = r2 & 3;
                const float4 g0 = wg[n * 320 + c * 32 + (2 * d2) * 4 + eqs];
                const float4 g1 = wg[n * 320 + c * 32 + (2 * d2 + 1) * 4 + eqs];
                wlds[((n * C_ + c) * 4 + d2) * 4 + eqs] =
                    make_uint4(pkh(g0.x, g1.x), pkh(g0.y, g1.y),
                               pkh(g0.z, g1.z), pkh(g0.w, g1.w));
            }
        }
    }
    // ---- stage x -> LDS fp16 d-pair words [n][b][4] ----
    {
        const float4* xg = (const float4*)x;
#pragma unroll
        for (int k = 0; k < 2; ++k) {
            const int g = k * 512 + tid;          // [0, 1024)
            const int b = g >> 4;
            const int r = g & 15;
            const int n = r >> 1;
            const int dq = r & 1;
            const float4 v = xg[((size_t)b * N_ + n0 + n) * 2 + dq];
            *(uint2*)&xlds[(n * B_ + b) * 4 + dq * 2] =
                make_uint2(pkh(v.x, v.y), pkh(v.z, v.w));
        }
    }
    __syncthreads();

    const int wv   = tid >> 6;
    const int lane = tid & 63;
    const int eq   = lane & 3;
    const int bl   = lane >> 2;
    const int h    = wv & 1;
    const int cg   = (wv >> 1) & 1;    // c-half: 0 -> c 0..4, 1 -> c 5..9
    const int np   = wv >> 2;          // n-half: 4 n each
    const int b0   = h * 32 + bl;
    const int b1   = b0 + 16;
    const int cbase = cg * 5;
    // xch slot: [buf][cg][np*2+h][bl][2]
    float* xme = xch + (((cg) * 4 + np * 2 + h) * 16 + bl) * 2;
    float* xot = xch + (((cg ^ 1) * 4 + np * 2 + h) * 16 + bl) * 2;

    unsigned vcp0[5][2], vcp1[5][2];
    if (!UNIFORM) {
#pragma unroll
        for (int cc = 0; cc < 5; ++cc) {
            const int c = cbase + cc;
            const uint2 a = *(const uint2*)(vpk + (b0 * C_ + c) * 8 + eq * 2);
            vcp0[cc][0] = a.x; vcp0[cc][1] = a.y;
            const uint2 d = *(const uint2*)(vpk + (b1 * C_ + c) * 8 + eq * 2);
            vcp1[cc][0] = d.x; vcp1[cc][1] = d.y;
        }
    }

    float4 acc0[5], acc1[5];
#pragma unroll
    for (int cc = 0; cc < 5; ++cc) {
        acc0[cc] = make_float4(0.f, 0.f, 0.f, 0.f);
        acc1[cc] = make_float4(0.f, 0.f, 0.f, 0.f);
    }

#pragma unroll 1
    for (int j = 0; j < 4; ++j) {
        const int nl = np * 4 + j;
        const uint4 xq0 = *(const uint4*)&xlds[(nl * B_ + b0) * 4];
        const uint4 xq1 = *(const uint4*)&xlds[(nl * B_ + b1) * 4];
        const unsigned xa[4] = {xq0.x, xq0.y, xq0.z, xq0.w};
        const unsigned xb[4] = {xq1.x, xq1.y, xq1.z, xq1.w};

        if (UNIFORM) {
#pragma unroll
            for (int cc = 0; cc < 5; ++cc) {
                const uint4* wq = &wlds[(nl * C_ + cbase + cc) * 16];
#pragma unroll
                for (int d2 = 0; d2 < 4; ++d2) {
                    const uint4 q = wq[d2 * 4 + eq];
                    acc0[cc].x = fd2(xa[d2], q.x, acc0[cc].x);
                    acc0[cc].y = fd2(xa[d2], q.y, acc0[cc].y);
                    acc0[cc].z = fd2(xa[d2], q.z, acc0[cc].z);
                    acc0[cc].w = fd2(xa[d2], q.w, acc0[cc].w);
                    acc1[cc].x = fd2(xb[d2], q.x, acc1[cc].x);
                    acc1[cc].y = fd2(xb[d2], q.y, acc1[cc].y);
                    acc1[cc].z = fd2(xb[d2], q.z, acc1[cc].z);
                    acc1[cc].w = fd2(xb[d2], q.w, acc1[cc].w);
                }
            }
        } else {
            unsigned uhp0[5][2], uhp1[5][2];
            float wgt0[5], wgt1[5];
            float s0 = 0.f, s1 = 0.f;
#pragma unroll
            for (int cc = 0; cc < 5; ++cc) {
                const uint4* wq = &wlds[(nl * C_ + cbase + cc) * 16];
                float4 u0 = make_float4(0.f, 0.f, 0.f, 0.f);
                float4 u1 = make_float4(0.f, 0.f, 0.f, 0.f);
#pragma unroll
                for (int d2 = 0; d2 < 4; ++d2) {
                    const uint4 q = wq[d2 * 4 + eq];
                    u0.x = fd2(xa[d2], q.x, u0.x);
                    u0.y = fd2(xa[d2], q.y, u0.y);
                    u0.z = fd2(xa[d2], q.z, u0.z);
                    u0.w = fd2(xa[d2], q.w, u0.w);
                    u1.x = fd2(xb[d2], q.x, u1.x);
                    u1.y = fd2(xb[d2], q.y, u1.y);
                    u1.z = fd2(xb[d2], q.z, u1.z);
                    u1.w = fd2(xb[d2], q.w, u1.w);
                }
                const unsigned up00 = pkh(u0.x, u0.y), up01 = pkh(u0.z, u0.w);
                const unsigned up10 = pkh(u1.x, u1.y), up11 = pkh(u1.z, u1.w);
                float t0 = fd2(up00, vcp0[cc][0], fd2(up01, vcp0[cc][1], 0.f));
                t0 += __shfl_xor(t0, 1); t0 += __shfl_xor(t0, 2);
                float t1 = fd2(up10, vcp1[cc][0], fd2(up11, vcp1[cc][1], 0.f));
                t1 += __shfl_xor(t1, 1); t1 += __shfl_xor(t1, 2);
                wgt0[cc] = __expf(t0); s0 += wgt0[cc];
                wgt1[cc] = __expf(t1); s1 += wgt1[cc];
                uhp0[cc][0] = up00; uhp0[cc][1] = up01;
                uhp1[cc][0] = up10; uhp1[cc][1] = up11;
            }
            // exchange the 5-class exp-sums with the other c-half
            if (eq == 0) { xme[0] = s0; xme[1] = s1; }
            __syncthreads();
            const float i0 = 1.f / (s0 + xot[0]);
            const float i1 = 1.f / (s1 + xot[1]);
#pragma unroll
            for (int cc = 0; cc < 5; ++cc) {
                const float g0 = wgt0[cc] * i0, g1 = wgt1[cc] * i1;
                acc0[cc].x = fmaf(g0, hlo(uhp0[cc][0]), acc0[cc].x);
                acc0[cc].y = fmaf(g0, hhi(uhp0[cc][0]), acc0[cc].y);
                acc0[cc].z = fmaf(g0, hlo(uhp0[cc][1]), acc0[cc].z);
                acc0[cc].w = fmaf(g0, hhi(uhp0[cc][1]), acc0[cc].w);
                acc1[cc].x = fmaf(g1, hlo(uhp1[cc][0]), acc1[cc].x);
                acc1[cc].y = fmaf(g1, hhi(uhp1[cc][0]), acc1[cc].y);
                acc1[cc].z = fmaf(g1, hlo(uhp1[cc][1]), acc1[cc].z);
                acc1[cc].w = fmaf(g1, hhi(uhp1[cc][1]), acc1[cc].w);
            }
        }
    }

    // ---- combine np halves via fp16 LDS (alias over dead W/x) ----
    const float fold = UNIFORM ? 0.1f : 1.f;   // softmax(0) = 1/10 folded out
    __syncthreads();   // all wlds/xlds reads done; smem becomes wb
    if (np == 1) {
#pragma unroll
        for (int cc = 0; cc < 5; ++cc) {
            const int c = cbase + cc;
            *(uint2*)&wb[b0 * WBROW_ + c * 8 + eq * 2] =
                make_uint2(hpack(acc0[cc].x * fold, acc0[cc].y * fold),
                           hpack(acc0[cc].z * fold, acc0[cc].w * fold));
            *(uint2*)&wb[b1 * WBROW_ + c * 8 + eq * 2] =
                make_uint2(hpack(acc1[cc].x * fold, acc1[cc].y * fold),
                           hpack(acc1[cc].z * fold, acc1[cc].w * fold));
        }
    }
    __syncthreads();
    if (np == 0) {
#pragma unroll
        for (int cc = 0; cc < 5; ++cc) {
            const int c = cbase + cc;
            const uint2 p0 = *(const uint2*)&wb[b0 * WBROW_ + c * 8 + eq * 2];
            const float2 a0 = hunpack(p0.x), a1 = hunpack(p0.y);
            *(uint2*)(partial + ((size_t)b0 * NSLOT_ + blk) * PROW_ + c * 8 + eq * 2) =
                make_uint2(hpack(a0.x + acc0[cc].x * fold, a0.y + acc0[cc].y * fold),
                           hpack(a1.x + acc0[cc].z * fold, a1.y + acc0[cc].w * fold));
            const uint2 p1 = *(const uint2*)&wb[b1 * WBROW_ + c * 8 + eq * 2];
            const float2 d0 = hunpack(p1.x), d1 = hunpack(p1.y);
            *(uint2*)(partial + ((size_t)b1 * NSLOT_ + blk) * PROW_ + c * 8 + eq * 2) =
                make_uint2(hpack(d0.x + acc1[cc].x * fold, d0.y + acc1[cc].y * fold),
                           hpack(d1.x + acc1[cc].z * fold, d1.y + acc1[cc].w * fold));
        }
    }
}

// Reduce stage A: 512 blocks = (b, sg); sum 64 slots -> sub[b][sg][160] f32.
__global__ __launch_bounds__(256) void caps_redA(
    const unsigned* __restrict__ partial, float* __restrict__ sub)
{
    const int b  = (int)blockIdx.x >> 3;
    const int sg = (int)blockIdx.x & 7;
    const int tid = (int)threadIdx.x;
    const int sc   = tid >> 5;          // 0..7
    const int col4 = tid & 31;          // active < 20
    __shared__ float red[8][20][8];
    if (col4 < 20) {
        float s[8];
#pragma unroll
        for (int p = 0; p < 8; ++p) s[p] = 0.f;
        const int slot0 = sg * (NSLOT_ / NSG_) + sc * 8;
        const uint4* base = (const uint4*)(partial +
            ((size_t)b * NSLOT_ + slot0) * PROW_) + col4;
#pragma unroll 4
        for (int k = 0; k < 8; ++k) {
            const uint4 q = base[k * (PROW_ / 4)];
            const float2 f0 = hunpack(q.x), f1 = hunpack(q.y);
            const float2 f2 = hunpack(q.z), f3 = hunpack(q.w);
            s[0] += f0.x; s[1] += f0.y; s[2] += f1.x; s[3] += f1.y;
            s[4] += f2.x; s[5] += f2.y; s[6] += f3.x; s[7] += f3.y;
        }
#pragma unroll
        for (int p = 0; p < 8; ++p) red[sc][col4][p] = s[p];
    }
    __syncthreads();
    if (tid < 160) {
        const int c4 = tid >> 3, p = tid & 7;
        float s = 0.f;
#pragma unroll
        for (int ch = 0; ch < 8; ++ch) s += red[ch][c4][p];
        sub[((size_t)b * NSG_ + sg) * (C_ * E_) + c4 * 8 + p] = s;
    }
}

// Reduce stage B: 64 blocks x 128 thr; 80 active pair-threads per b.
// Writes f32 v_cum AND packed-fp16 vpk in the pass's vcp word order.
// mode: 0 = v_cum = v, 1 = v_cum += v, 2 = out = v
__global__ __launch_bounds__(128) void caps_redB(
    const float* __restrict__ sub, float* __restrict__ v_cum,
    unsigned* __restrict__ vpk, float* __restrict__ out, int mode)
{
    const int b = (int)blockIdx.x;
    const int tid = (int)threadIdx.x;
    if (tid >= PROW_) return;
    float slo = 0.f, shi = 0.f;
#pragma unroll
    for (int sg = 0; sg < NSG_; ++sg) {
        const float* p = sub + ((size_t)b * NSG_ + sg) * (C_ * E_) + tid * 2;
        slo += p[0]; shi += p[1];
    }
    float p = slo * slo + shi * shi;     // sum over the 16 e of this c
    p += __shfl_xor(p, 1); p += __shfl_xor(p, 2); p += __shfl_xor(p, 4);
    const float sc = (p / (1.f + p)) * rsqrtf(p + EPS_);
    float v0 = sc * slo, v1 = sc * shi;
    const int o = b * (C_ * E_) + tid * 2;
    if (mode == 2) {
        out[o] = v0; out[o + 1] = v1;
    } else {
        if (mode == 0) {
            v_cum[o] = v0; v_cum[o + 1] = v1;
        } else {
            v0 += v_cum[o]; v1 += v_cum[o + 1];
            v_cum[o] = v0; v_cum[o + 1] = v1;
        }
        vpk[b * PROW_ + tid] = hpack(v0, v1);
    }
}

extern "C" void kernel_launch(void* const* d_in, const int* in_sizes, int n_in,
                              void* d_out, int out_size, void* d_ws, size_t ws_size,
                              hipStream_t stream) {
    const float* x = (const float*)d_in[0];
    const float* W = (const float*)d_in[1];
    float* out = (float*)d_out;

    // ws: partial 10.49 MB | sub 327 KB | v_cum 40 KB | vpk 20 KB
    char* p = (char*)d_ws;
    unsigned* partial = (unsigned*)p;
    p += (size_t)B_ * NSLOT_ * PROW_ * sizeof(unsigned);
    float* sub = (float*)p;
    p += (size_t)B_ * NSG_ * C_ * E_ * sizeof(float);
    float* v_cum = (float*)p;
    p += (size_t)B_ * C_ * E_ * sizeof(float);
    unsigned* vpk = (unsigned*)p;

    for (int t = 0; t < 3; ++t) {
        if (t == 0)
            caps_pass<true ><<<dim3(NBLK_), 512, 0, stream>>>(x, W, vpk, partial);
        else
            caps_pass<false><<<dim3(NBLK_), 512, 0, stream>>>(x, W, vpk, partial);
        caps_redA<<<dim3(B_ * NSG_), 256, 0, stream>>>(partial, sub);
        caps_redB<<<dim3(B_), 128, 0, stream>>>(sub, v_cum, vpk, out, t);
    }
}

// Round 26
// 77.968 us; speedup vs baseline: 2.4806x; 1.0033x over previous
//
#include <hip/hip_runtime.h>
#include <hip/hip_fp16.h>

#define B_ 64
#define N_ 4096
#define C_ 10
#define D_ 8
#define E_ 16
#define EPS_ 1e-7f
#define NT_ 8
#define NBLK_ (N_ / NT_)          // 512 pass blocks
#define NSLOT_ NBLK_              // 512 partial slots (1 per block)
#define PROW_ 80                  // u32 per partial row (160 halfs)
#define WBROW_ 82                 // padded LDS combine row stride (u32)

typedef _Float16 h2_t __attribute__((ext_vector_type(2)));
typedef __fp16   p2_t __attribute__((ext_vector_type(2)));   // cvt_pkrtz ret type

__device__ inline unsigned pkh(float a, float b) {   // f32x2 -> packed fp16
    p2_t t = __builtin_amdgcn_cvt_pkrtz(a, b);
    return *(unsigned*)&t;
}
#if __has_builtin(__builtin_amdgcn_fdot2)
__device__ inline float fd2(unsigned a, unsigned b, float c) {
    h2_t av = *(h2_t*)&a, bv = *(h2_t*)&b;
    return __builtin_amdgcn_fdot2(av, bv, c, false);
}
#else
__device__ inline float fd2(unsigned a, unsigned b, float c) {
    h2_t av = *(h2_t*)&a, bv = *(h2_t*)&b;
    return fmaf((float)av.x, (float)bv.x, fmaf((float)av.y, (float)bv.y, c));
}
#endif
__device__ inline float hlo(unsigned u) { h2_t t = *(h2_t*)&u; return (float)t.x; }
__device__ inline float hhi(unsigned u) { h2_t t = *(h2_t*)&u; return (float)t.y; }
__device__ inline unsigned hpack(float a, float b) {
    __half2 t = __floats2half2_rn(a, b);
    return *(unsigned*)&t;
}
__device__ inline float2 hunpack(unsigned u) {
    return __half22float2(*(const __half2*)&u);
}

// Block: 512 thr = 8 waves = (h: b-half) x (cg: c-half) x (np: n-half).
// Thread owns TWO b (b0=h*32+bl, b1=b0+16), FIVE c, 4 n (np half of NT=8).
// fp16 d-pair data, v_dot2_f32_f16 contraction; v_cum arrives pre-packed
// (vpk). np halves combine via fp16 LDS buffer (aliased over dead W tile)
// -> ONE slot per block: partial = 10.5 MB. (R22 — best measured: 78.0 us.)
template <bool UNIFORM>
__global__ __launch_bounds__(512, 4) void caps_pass(
    const float* __restrict__ x, const float* __restrict__ W,
    const unsigned* __restrict__ vpk, unsigned* __restrict__ partial)
{
    __shared__ __align__(16) char smem[30720];
    uint4*    wlds = (uint4*)smem;                   // 1280 uint4 = 20480 B
    unsigned* xlds = (unsigned*)(smem + 20480);      // 2048 u32  =  8192 B
    float*    xch  = (float*)(smem + 28672);         // 512 f32   =  2048 B
    unsigned* wb   = (unsigned*)smem;                // combine alias (20992 B)

    const int tid = (int)threadIdx.x;
    const int blk = (int)blockIdx.x;
    const int n0  = blk * NT_;

    // ---- stage W -> LDS fp16 d-pair granules [n][c][d2][eq] ----
    {
        const float4* wg = (const float4*)W + (size_t)blk * (NT_ * 320);
#pragma unroll
        for (int k = 0; k < 3; ++k) {
            const int g = k * 512 + tid;          // [0, 1280)
            if (g < NT_ * C_ * 16) {
                const int n   = g / 160;
                const int rem = g - n * 160;
                const int c   = rem >> 4;
                const int r2  = rem & 15;
                const int d2  = r2 >> 2;
                const int eqs = r2 & 3;
                const float4 g0 = wg[n * 320 + c * 32 + (2 * d2) * 4 + eqs];
                const float4 g1 = wg[n * 320 + c * 32 + (2 * d2 + 1) * 4 + eqs];
                wlds[((n * C_ + c) * 4 + d2) * 4 + eqs] =
                    make_uint4(pkh(g0.x, g1.x), pkh(g0.y, g1.y),
                               pkh(g0.z, g1.z), pkh(g0.w, g1.w));
            }
        }
    }
    // ---- stage x -> LDS fp16 d-pair words [n][b][4] ----
    {
        const float4* xg = (const float4*)x;
#pragma unroll
        for (int k = 0; k < 2; ++k) {
            const int g = k * 512 + tid;          // [0, 1024)
            const int b = g >> 4;
            const int r = g & 15;
            const int n = r >> 1;
            const int dq = r & 1;
            const float4 v = xg[((size_t)b * N_ + n0 + n) * 2 + dq];
            *(uint2*)&xlds[(n * B_ + b) * 4 + dq * 2] =
                make_uint2(pkh(v.x, v.y), pkh(v.z, v.w));
        }
    }
    __syncthreads();

    const int wv   = tid >> 6;
    const int lane = tid & 63;
    const int eq   = lane & 3;
    const int bl   = lane >> 2;
    const int h    = wv & 1;
    const int cg   = (wv >> 1) & 1;    // c-half: 0 -> c 0..4, 1 -> c 5..9
    const int np   = wv >> 2;          // n-half: 4 n each
    const int b0   = h * 32 + bl;
    const int b1   = b0 + 16;
    const int cbase = cg * 5;
    // xch slot: [cg][np*2+h][bl][2]
    float* xme = xch + (((cg) * 4 + np * 2 + h) * 16 + bl) * 2;
    float* xot = xch + (((cg ^ 1) * 4 + np * 2 + h) * 16 + bl) * 2;

    unsigned vcp0[5][2], vcp1[5][2];
    if (!UNIFORM) {
#pragma unroll
        for (int cc = 0; cc < 5; ++cc) {
            const int c = cbase + cc;
            const uint2 a = *(const uint2*)(vpk + (b0 * C_ + c) * 8 + eq * 2);
            vcp0[cc][0] = a.x; vcp0[cc][1] = a.y;
            const uint2 d = *(const uint2*)(vpk + (b1 * C_ + c) * 8 + eq * 2);
            vcp1[cc][0] = d.x; vcp1[cc][1] = d.y;
        }
    }

    float4 acc0[5], acc1[5];
#pragma unroll
    for (int cc = 0; cc < 5; ++cc) {
        acc0[cc] = make_float4(0.f, 0.f, 0.f, 0.f);
        acc1[cc] = make_float4(0.f, 0.f, 0.f, 0.f);
    }

#pragma unroll 1
    for (int j = 0; j < 4; ++j) {
        const int nl = np * 4 + j;
        const uint4 xq0 = *(const uint4*)&xlds[(nl * B_ + b0) * 4];
        const uint4 xq1 = *(const uint4*)&xlds[(nl * B_ + b1) * 4];
        const unsigned xa[4] = {xq0.x, xq0.y, xq0.z, xq0.w};
        const unsigned xb[4] = {xq1.x, xq1.y, xq1.z, xq1.w};

        if (UNIFORM) {
#pragma unroll
            for (int cc = 0; cc < 5; ++cc) {
                const uint4* wq = &wlds[(nl * C_ + cbase + cc) * 16];
#pragma unroll
                for (int d2 = 0; d2 < 4; ++d2) {
                    const uint4 q = wq[d2 * 4 + eq];
                    acc0[cc].x = fd2(xa[d2], q.x, acc0[cc].x);
                    acc0[cc].y = fd2(xa[d2], q.y, acc0[cc].y);
                    acc0[cc].z = fd2(xa[d2], q.z, acc0[cc].z);
                    acc0[cc].w = fd2(xa[d2], q.w, acc0[cc].w);
                    acc1[cc].x = fd2(xb[d2], q.x, acc1[cc].x);
                    acc1[cc].y = fd2(xb[d2], q.y, acc1[cc].y);
                    acc1[cc].z = fd2(xb[d2], q.z, acc1[cc].z);
                    acc1[cc].w = fd2(xb[d2], q.w, acc1[cc].w);
                }
            }
        } else {
            unsigned uhp0[5][2], uhp1[5][2];
            float wgt0[5], wgt1[5];
            float s0 = 0.f, s1 = 0.f;
#pragma unroll
            for (int cc = 0; cc < 5; ++cc) {
                const uint4* wq = &wlds[(nl * C_ + cbase + cc) * 16];
                float4 u0 = make_float4(0.f, 0.f, 0.f, 0.f);
                float4 u1 = make_float4(0.f, 0.f, 0.f, 0.f);
#pragma unroll
                for (int d2 = 0; d2 < 4; ++d2) {
                    const uint4 q = wq[d2 * 4 + eq];
                    u0.x = fd2(xa[d2], q.x, u0.x);
                    u0.y = fd2(xa[d2], q.y, u0.y);
                    u0.z = fd2(xa[d2], q.z, u0.z);
                    u0.w = fd2(xa[d2], q.w, u0.w);
                    u1.x = fd2(xb[d2], q.x, u1.x);
                    u1.y = fd2(xb[d2], q.y, u1.y);
                    u1.z = fd2(xb[d2], q.z, u1.z);
                    u1.w = fd2(xb[d2], q.w, u1.w);
                }
                const unsigned up00 = pkh(u0.x, u0.y), up01 = pkh(u0.z, u0.w);
                const unsigned up10 = pkh(u1.x, u1.y), up11 = pkh(u1.z, u1.w);
                float t0 = fd2(up00, vcp0[cc][0], fd2(up01, vcp0[cc][1], 0.f));
                t0 += __shfl_xor(t0, 1); t0 += __shfl_xor(t0, 2);
                float t1 = fd2(up10, vcp1[cc][0], fd2(up11, vcp1[cc][1], 0.f));
                t1 += __shfl_xor(t1, 1); t1 += __shfl_xor(t1, 2);
                wgt0[cc] = __expf(t0); s0 += wgt0[cc];
                wgt1[cc] = __expf(t1); s1 += wgt1[cc];
                uhp0[cc][0] = up00; uhp0[cc][1] = up01;
                uhp1[cc][0] = up10; uhp1[cc][1] = up11;
            }
            // exchange the 5-class exp-sums with the other c-half
            if (eq == 0) { xme[0] = s0; xme[1] = s1; }
            __syncthreads();
            const float i0 = 1.f / (s0 + xot[0]);
            const float i1 = 1.f / (s1 + xot[1]);
#pragma unroll
            for (int cc = 0; cc < 5; ++cc) {
                const float g0 = wgt0[cc] * i0, g1 = wgt1[cc] * i1;
                acc0[cc].x = fmaf(g0, hlo(uhp0[cc][0]), acc0[cc].x);
                acc0[cc].y = fmaf(g0, hhi(uhp0[cc][0]), acc0[cc].y);
                acc0[cc].z = fmaf(g0, hlo(uhp0[cc][1]), acc0[cc].z);
                acc0[cc].w = fmaf(g0, hhi(uhp0[cc][1]), acc0[cc].w);
                acc1[cc].x = fmaf(g1, hlo(uhp1[cc][0]), acc1[cc].x);
                acc1[cc].y = fmaf(g1, hhi(uhp1[cc][0]), acc1[cc].y);
                acc1[cc].z = fmaf(g1, hlo(uhp1[cc][1]), acc1[cc].z);
                acc1[cc].w = fmaf(g1, hhi(uhp1[cc][1]), acc1[cc].w);
            }
        }
    }

    // ---- combine np halves via fp16 LDS (alias over dead W/x) ----
    const float fold = UNIFORM ? 0.1f : 1.f;   // softmax(0) = 1/10 folded out
    __syncthreads();   // all wlds/xlds reads done; smem becomes wb
    if (np == 1) {
#pragma unroll
        for (int cc = 0; cc < 5; ++cc) {
            const int c = cbase + cc;
            *(uint2*)&wb[b0 * WBROW_ + c * 8 + eq * 2] =
                make_uint2(hpack(acc0[cc].x * fold, acc0[cc].y * fold),
                           hpack(acc0[cc].z * fold, acc0[cc].w * fold));
            *(uint2*)&wb[b1 * WBROW_ + c * 8 + eq * 2] =
                make_uint2(hpack(acc1[cc].x * fold, acc1[cc].y * fold),
                           hpack(acc1[cc].z * fold, acc1[cc].w * fold));
        }
    }
    __syncthreads();
    if (np == 0) {
#pragma unroll
        for (int cc = 0; cc < 5; ++cc) {
            const int c = cbase + cc;
            const uint2 p0 = *(const uint2*)&wb[b0 * WBROW_ + c * 8 + eq * 2];
            const float2 a0 = hunpack(p0.x), a1 = hunpack(p0.y);
            *(uint2*)(partial + ((size_t)b0 * NSLOT_ + blk) * PROW_ + c * 8 + eq * 2) =
                make_uint2(hpack(a0.x + acc0[cc].x * fold, a0.y + acc0[cc].y * fold),
                           hpack(a1.x + acc0[cc].z * fold, a1.y + acc0[cc].w * fold));
            const uint2 p1 = *(const uint2*)&wb[b1 * WBROW_ + c * 8 + eq * 2];
            const float2 d0 = hunpack(p1.x), d1 = hunpack(p1.y);
            *(uint2*)(partial + ((size_t)b1 * NSLOT_ + blk) * PROW_ + c * 8 + eq * 2) =
                make_uint2(hpack(d0.x + acc1[cc].x * fold, d0.y + acc1[cc].y * fold),
                           hpack(d1.x + acc1[cc].z * fold, d1.y + acc1[cc].w * fold));
        }
    }
}

// Fused reduce: 64 blocks (one per b) x 512 thr.
// Phase 1: (sc: 16 chunks of 32 slots) x (col4: 20 uint4 cols): each thread
// 32 coalesced uint4 row-loads (redA's proven pattern, wider block).
// Phase 2: 160 threads fold 16 chunks -> ssum[160] in LDS.
// Phase 3: 80 pair-threads squash via 8-lane shfl (redB's exact pattern),
// update v_cum/vpk or write out. mode: 0 = set, 1 = add, 2 = out.
__global__ __launch_bounds__(512) void caps_red(
    const unsigned* __restrict__ partial, float* __restrict__ v_cum,
    unsigned* __restrict__ vpk, float* __restrict__ out, int mode)
{
    const int b = (int)blockIdx.x;
    const int tid = (int)threadIdx.x;
    const int sc   = tid >> 5;          // 0..15
    const int col4 = tid & 31;          // active < 20
    __shared__ float red[16][20][8];    // 10240 B
    __shared__ float ssum[160];
    if (col4 < 20) {
        float s[8];
#pragma unroll
        for (int p = 0; p < 8; ++p) s[p] = 0.f;
        const uint4* base = (const uint4*)(partial +
            ((size_t)b * NSLOT_ + sc * 32) * PROW_) + col4;
#pragma unroll 4
        for (int k = 0; k < 32; ++k) {
            const uint4 q = base[k * (PROW_ / 4)];
            const float2 f0 = hunpack(q.x), f1 = hunpack(q.y);
            const float2 f2 = hunpack(q.z), f3 = hunpack(q.w);
            s[0] += f0.x; s[1] += f0.y; s[2] += f1.x; s[3] += f1.y;
            s[4] += f2.x; s[5] += f2.y; s[6] += f3.x; s[7] += f3.y;
        }
#pragma unroll
        for (int p = 0; p < 8; ++p) red[sc][col4][p] = s[p];
    }
    __syncthreads();
    if (tid < 160) {
        const int c4 = tid >> 3, p = tid & 7;
        float s = 0.f;
#pragma unroll
        for (int ch = 0; ch < 16; ++ch) s += red[ch][c4][p];
        ssum[c4 * 8 + p] = s;
    }
    __syncthreads();
    if (tid < PROW_) {
        const float slo = ssum[tid * 2];
        const float shi = ssum[tid * 2 + 1];
        float p = slo * slo + shi * shi;    // sum over the 16 e of this c
        p += __shfl_xor(p, 1); p += __shfl_xor(p, 2); p += __shfl_xor(p, 4);
        const float sc2 = (p / (1.f + p)) * rsqrtf(p + EPS_);
        float v0 = sc2 * slo, v1 = sc2 * shi;
        const int o = b * (C_ * E_) + tid * 2;
        if (mode == 2) {
            out[o] = v0; out[o + 1] = v1;
        } else {
            if (mode == 0) {
                v_cum[o] = v0; v_cum[o + 1] = v1;
            } else {
                v0 += v_cum[o]; v1 += v_cum[o + 1];
                v_cum[o] = v0; v_cum[o + 1] = v1;
            }
            vpk[b * PROW_ + tid] = hpack(v0, v1);
        }
    }
}

extern "C" void kernel_launch(void* const* d_in, const int* in_sizes, int n_in,
                              void* d_out, int out_size, void* d_ws, size_t ws_size,
                              hipStream_t stream) {
    const float* x = (const float*)d_in[0];
    const float* W = (const float*)d_in[1];
    float* out = (float*)d_out;

    // ws: partial 10.49 MB | v_cum 40 KB | vpk 20 KB
    char* p = (char*)d_ws;
    unsigned* partial = (unsigned*)p;
    p += (size_t)B_ * NSLOT_ * PROW_ * sizeof(unsigned);
    float* v_cum = (float*)p;
    p += (size_t)B_ * C_ * E_ * sizeof(float);
    unsigned* vpk = (unsigned*)p;

    for (int t = 0; t < 3; ++t) {
        if (t == 0)
            caps_pass<true ><<<dim3(NBLK_), 512, 0, stream>>>(x, W, vpk, partial);
        else
            caps_pass<false><<<dim3(NBLK_), 512, 0, stream>>>(x, W, vpk, partial);
        caps_red<<<dim3(B_), 512, 0, stream>>>(partial, v_cum, vpk, out, t);
    }
}